// Round 10
// baseline (751.999 us; speedup 1.0000x reference)
//
#include <hip/hip_runtime.h>
#include <hip/hip_bf16.h>

// PointCraft++: 6 transformer blocks (local MHA within 64-token parts +
// cross MHA to 49 image tokens) over a (64, 512, 256) state stream.
// Round 10: attn softmax streamlined — no max-sub (scores bounded), P stored
// unnormalized, row-sums via MFMA ones-column, O normalized at the end;
// P->PV sync is wave-local (P/Vt are per-wave). Rest identical to round 9.

#define B_     64
#define P_     8
#define T_     64
#define S_     512
#define D_     256
#define H_     8
#define DH_    32
#define NIMG_  49
#define M_ST   32768
#define M_IMG  3136

#define AS1 __attribute__((address_space(1)))
#define AS3 __attribute__((address_space(3)))

typedef short bf16x8 __attribute__((ext_vector_type(8)));
typedef float f32x4  __attribute__((ext_vector_type(4)));

__device__ inline uint f2b_pk(float x, float y) {
    uint bx = __float_as_uint(x), by = __float_as_uint(y);
    bx = (bx + 0x7FFFu + ((bx >> 16) & 1u)) >> 16;
    by = (by + 0x7FFFu + ((by >> 16) & 1u)) >> 16;
    return bx | (by << 16);
}
__device__ inline ushort f2b(float x) {
    uint b = __float_as_uint(x);
    return (ushort)((b + 0x7FFFu + ((b >> 16) & 1u)) >> 16);
}
__device__ inline float b2f(ushort u) {
    return __uint_as_float(((uint)u) << 16);
}

// ---------------------------------------------------------------------------
// fp32 -> bf16 conversion (weights + feat, one-time per launch)
// ---------------------------------------------------------------------------
__global__ __launch_bounds__(256) void cvt_bf16x4(
    const float4* __restrict__ in, uint2* __restrict__ out, int n4)
{
    int i = blockIdx.x * 256 + threadIdx.x;
    if (i < n4) {
        float4 v = in[i];
        out[i] = make_uint2(f2b_pk(v.x, v.y), f2b_pk(v.z, v.w));
    }
}

// ---------------------------------------------------------------------------
// MFMA GEMM (small): 128x128 tile, BK=32, 4 waves. Used for M_IMG precompute.
// ---------------------------------------------------------------------------
__global__ __launch_bounds__(256) void gemm_bf16(
    const ushort* __restrict__ A,
    const ushort* __restrict__ W,
    const float*  __restrict__ bias,
    ushort*       __restrict__ C,
    int M, int N, int K)
{
    __shared__ ushort smem[128 * 128];
    ushort* Asm = smem;
    ushort* Bsm = smem + 4096;

    const int tid  = threadIdx.x;
    const int lane = tid & 63;
    const int wave = tid >> 6;
    const int wr = wave >> 1, wc = wave & 1;
    const int row0 = blockIdx.x * 128, col0 = blockIdx.y * 128;

    f32x4 acc[4][4] = {};

    const int skc = (tid & 3) * 8;
    const int sr0 = tid >> 2;
    const int fr  = lane & 15;
    const int g   = lane >> 4;

    for (int k0 = 0; k0 < K; k0 += 32) {
        #pragma unroll
        for (int i = 0; i < 2; ++i) {
            const int r = sr0 + i * 64;
            const int e = (tid + i * 256) * 8;
            int ra = row0 + r; if (ra >= M) ra = M - 1;
            __builtin_amdgcn_global_load_lds(
                (const AS1 void*)(A + (size_t)ra * K + k0 + skc),
                (AS3 void*)&Asm[e], 16, 0, 0);
            __builtin_amdgcn_global_load_lds(
                (const AS1 void*)(W + (size_t)(col0 + r) * K + k0 + skc),
                (AS3 void*)&Bsm[e], 16, 0, 0);
        }
        __syncthreads();

        bf16x8 af[4], bf[4];
        #pragma unroll
        for (int i = 0; i < 4; ++i)
            af[i] = *reinterpret_cast<const bf16x8*>(&Asm[(wr * 64 + i * 16 + fr) * 32 + g * 8]);
        #pragma unroll
        for (int j = 0; j < 4; ++j)
            bf[j] = *reinterpret_cast<const bf16x8*>(&Bsm[(wc * 64 + j * 16 + fr) * 32 + g * 8]);
        #pragma unroll
        for (int i = 0; i < 4; ++i)
            #pragma unroll
            for (int j = 0; j < 4; ++j)
                acc[i][j] = __builtin_amdgcn_mfma_f32_16x16x32_bf16(
                    af[i], bf[j], acc[i][j], 0, 0, 0);
        __syncthreads();
    }

    float bn[4];
    #pragma unroll
    for (int j = 0; j < 4; ++j) bn[j] = bias[col0 + wc * 64 + j * 16 + fr];

    #pragma unroll
    for (int i = 0; i < 4; ++i)
        #pragma unroll
        for (int j = 0; j < 4; ++j)
            #pragma unroll
            for (int r = 0; r < 4; ++r)
                smem[(wr * 64 + i * 16 + g * 4 + r) * 128 + wc * 64 + j * 16 + fr] =
                    f2b(acc[i][j][r] + bn[j]);
    __syncthreads();

    #pragma unroll
    for (int it = 0; it < 8; ++it) {
        const int elem = (it * 256 + tid) * 8;
        const int lrow = elem >> 7, lcol = elem & 127;
        const int m = row0 + lrow;
        if (m < M)
            *reinterpret_cast<uint4*>(&C[(size_t)m * N + col0 + lcol]) =
                *reinterpret_cast<const uint4*>(&smem[elem]);
    }
}

// ---------------------------------------------------------------------------
// MFMA GEMM (big): BM=256, BN=128, BK=32, 512 threads = 8 waves (4x2).
// For M % 256 == 0 (M_ST projections). grid = (M/256, N/128).
// ---------------------------------------------------------------------------
__global__ __launch_bounds__(512, 4) void gemm_bf16_big(
    const ushort* __restrict__ A,
    const ushort* __restrict__ W,
    const float*  __restrict__ bias,
    ushort*       __restrict__ C,
    int N, int K)
{
    __shared__ ushort smem[16384];       // As [0,8192); Bs [8192,12288)
    ushort* Asm = smem;
    ushort* Bsm = smem + 8192;

    const int tid  = threadIdx.x;
    const int lane = tid & 63;
    const int wave = tid >> 6;           // 0..7
    const int wr = wave >> 1, wc = wave & 1;
    const int row0 = blockIdx.x * 256, col0 = blockIdx.y * 128;

    f32x4 acc[4][4] = {};
    const int skc = (tid & 3) * 8;
    const int sr0 = tid >> 2;            // 0..127
    const int fr  = lane & 15;
    const int g   = lane >> 4;

    for (int k0 = 0; k0 < K; k0 += 32) {
        #pragma unroll
        for (int i = 0; i < 2; ++i) {
            const int r = sr0 + i * 128;             // 0..255
            __builtin_amdgcn_global_load_lds(
                (const AS1 void*)(A + (size_t)(row0 + r) * K + k0 + skc),
                (AS3 void*)&Asm[(tid + i * 512) * 8], 16, 0, 0);
        }
        __builtin_amdgcn_global_load_lds(
            (const AS1 void*)(W + (size_t)(col0 + sr0) * K + k0 + skc),
            (AS3 void*)&Bsm[tid * 8], 16, 0, 0);
        __syncthreads();

        bf16x8 af[4], bf[4];
        #pragma unroll
        for (int i = 0; i < 4; ++i)
            af[i] = *reinterpret_cast<const bf16x8*>(&Asm[(wr * 64 + i * 16 + fr) * 32 + g * 8]);
        #pragma unroll
        for (int j = 0; j < 4; ++j)
            bf[j] = *reinterpret_cast<const bf16x8*>(&Bsm[(wc * 64 + j * 16 + fr) * 32 + g * 8]);
        #pragma unroll
        for (int i = 0; i < 4; ++i)
            #pragma unroll
            for (int j = 0; j < 4; ++j)
                acc[i][j] = __builtin_amdgcn_mfma_f32_16x16x32_bf16(
                    af[i], bf[j], acc[i][j], 0, 0, 0);
        __syncthreads();
    }

    float bn[4];
    #pragma unroll
    for (int j = 0; j < 4; ++j) bn[j] = bias[col0 + wc * 64 + j * 16 + fr];

    // epilogue: two 128x128 halves through LDS, coalesced 16B stores
    #pragma unroll
    for (int h2 = 0; h2 < 2; ++h2) {
        if ((wr >> 1) == h2) {
            const int lwr = wr & 1;
            #pragma unroll
            for (int i = 0; i < 4; ++i)
                #pragma unroll
                for (int j = 0; j < 4; ++j)
                    #pragma unroll
                    for (int r = 0; r < 4; ++r)
                        smem[(lwr * 64 + i * 16 + g * 4 + r) * 128 + wc * 64 + j * 16 + fr] =
                            f2b(acc[i][j][r] + bn[j]);
        }
        __syncthreads();
        #pragma unroll
        for (int it = 0; it < 4; ++it) {
            const int elem = (it * 512 + tid) * 8;
            const int lrow = elem >> 7, lcol = elem & 127;
            *reinterpret_cast<uint4*>(
                &C[(size_t)(row0 + h2 * 128 + lrow) * N + col0 + lcol]) =
                *reinterpret_cast<const uint4*>(&smem[elem]);
        }
        __syncthreads();
    }
}

// ---------------------------------------------------------------------------
// Fused out-proj GEMM + residual + LayerNorm, bf16 state (round-9 verbatim).
// BM=64, BN=256, BK=32, 256 threads = 4 waves. Grid = M/64 = 512.
// ---------------------------------------------------------------------------
__global__ __launch_bounds__(256) void gemm_ln(
    const ushort* __restrict__ A,
    const ushort* __restrict__ W,
    const float*  __restrict__ bias,
    ushort*       __restrict__ stb,
    const float*  __restrict__ lnw,
    const float*  __restrict__ lnb)
{
    __shared__ ushort As[64 * 32];
    __shared__ ushort Bs[256 * 32];
    __shared__ ushort Cs[64 * 256];
    __shared__ float  redS[64][4];
    __shared__ float  redS2[64][4];

    const int tid  = threadIdx.x;
    const int lane = tid & 63;
    const int wc   = tid >> 6;
    const int fr = lane & 15, g = lane >> 4;
    const int row0 = blockIdx.x * 64;

    f32x4 acc[4][4] = {};
    const int skc = (tid & 3) * 8;
    const int sr  = tid >> 2;

    for (int k0 = 0; k0 < 256; k0 += 32) {
        __builtin_amdgcn_global_load_lds(
            (const AS1 void*)(A + (size_t)(row0 + sr) * 256 + k0 + skc),
            (AS3 void*)&As[tid * 8], 16, 0, 0);
        #pragma unroll
        for (int q = 0; q < 4; ++q)
            __builtin_amdgcn_global_load_lds(
                (const AS1 void*)(W + (size_t)(sr + q * 64) * 256 + k0 + skc),
                (AS3 void*)&Bs[(tid + q * 256) * 8], 16, 0, 0);
        __syncthreads();

        bf16x8 af[4], bf[4];
        #pragma unroll
        for (int i = 0; i < 4; ++i)
            af[i] = *reinterpret_cast<const bf16x8*>(&As[(i * 16 + fr) * 32 + g * 8]);
        #pragma unroll
        for (int j = 0; j < 4; ++j)
            bf[j] = *reinterpret_cast<const bf16x8*>(&Bs[(wc * 64 + j * 16 + fr) * 32 + g * 8]);
        #pragma unroll
        for (int i = 0; i < 4; ++i)
            #pragma unroll
            for (int j = 0; j < 4; ++j)
                acc[i][j] = __builtin_amdgcn_mfma_f32_16x16x32_bf16(
                    af[i], bf[j], acc[i][j], 0, 0, 0);
        __syncthreads();
    }

    int   col[4]; float bv[4], wv[4], lb[4];
    #pragma unroll
    for (int j = 0; j < 4; ++j) {
        col[j] = wc * 64 + j * 16 + fr;
        bv[j]  = bias[col[j]];
        wv[j]  = lnw[col[j]];
        lb[j]  = lnb[col[j]];
    }

    // pass 1: x = acc + bias + stb(bf16); per-row partial sums -> LDS
    #pragma unroll
    for (int i = 0; i < 4; ++i)
        #pragma unroll
        for (int r = 0; r < 4; ++r) {
            const int rl = i * 16 + g * 4 + r;
            const size_t rb = (size_t)(row0 + rl) * 256;
            float s = 0.f, s2 = 0.f;
            #pragma unroll
            for (int j = 0; j < 4; ++j) {
                float x = acc[i][j][r] + bv[j] + b2f(stb[rb + col[j]]);
                acc[i][j][r] = x;
                s += x; s2 += x * x;
            }
            #pragma unroll
            for (int o = 1; o < 16; o <<= 1) {
                s  += __shfl_xor(s, o);
                s2 += __shfl_xor(s2, o);
            }
            if (fr == 0) { redS[rl][wc] = s; redS2[rl][wc] = s2; }
        }
    __syncthreads();

    // pass 2: normalize -> Cs (bf16)
    #pragma unroll
    for (int i = 0; i < 4; ++i)
        #pragma unroll
        for (int r = 0; r < 4; ++r) {
            const int rl = i * 16 + g * 4 + r;
            const float ts  = redS[rl][0] + redS[rl][1] + redS[rl][2] + redS[rl][3];
            const float ts2 = redS2[rl][0] + redS2[rl][1] + redS2[rl][2] + redS2[rl][3];
            const float mean = ts * (1.f / 256.f);
            const float var  = ts2 * (1.f / 256.f) - mean * mean;
            const float rs   = rsqrtf(var + 1e-5f);
            #pragma unroll
            for (int j = 0; j < 4; ++j) {
                const float y = (acc[i][j][r] - mean) * rs * wv[j] + lb[j];
                Cs[rl * 256 + col[j]] = f2b(y);
            }
        }
    __syncthreads();

    // coalesced stb store (64 x 256)
    #pragma unroll
    for (int it = 0; it < 8; ++it) {
        const int elem = (it * 256 + tid) * 8;
        const int rl = elem >> 8, c = elem & 255;
        *reinterpret_cast<uint4*>(&stb[(size_t)(row0 + rl) * 256 + c]) =
            *reinterpret_cast<const uint4*>(&Cs[elem]);
    }
}

// ---------------------------------------------------------------------------
// Fused MFMA attention. Grid 512, 4 waves, wave w handles heads {w, w+4}.
// Swapped QK^T; no max-sub (scores bounded by LN'd inputs x 0.02 weights);
// P stored UNNORMALIZED; row-sums via MFMA ones-column; O normalized at end.
// P->PV sync is wave-local (P/Vt are per-wave slices); the 3 remaining
// barriers guard the cross-wave Os overlay region. Os overlays P_lds.
// ---------------------------------------------------------------------------
template<int CROSS>
__global__ __launch_bounds__(256) void attn_mfma(
    const ushort* __restrict__ qsrc,
    const ushort* __restrict__ ksrc,
    const ushort* __restrict__ vsrc,
    ushort* __restrict__ out)
{
    constexpr int QSTR = CROSS ? 256 : 768;
    constexpr int KSTR = CROSS ? 256 : 768;

    const int bid = blockIdx.x;
    int qrow0, krow0;
    if (CROSS) { qrow0 = (bid >> 3) * 512 + (bid & 7) * 64; krow0 = (bid >> 3) * 49; }
    else       { qrow0 = bid * 64; krow0 = bid * 64; }

    __shared__ ushort P_lds[4][64][72];
    __shared__ ushort Vt_lds[4][32][72];
    ushort* Os = &P_lds[0][0][0];

    const int tid = threadIdx.x;
    const int w = tid >> 6, l = tid & 63;
    const int fr = l & 15, g = l >> 4;
    ushort (*P)[72]  = P_lds[w];
    ushort (*Vt)[72] = Vt_lds[w];

    // constant B-fragment: row 0 = ones (lanes fr==0), others 0
    bf16x8 vones = {};
    if (fr == 0) {
        #pragma unroll
        for (int e = 0; e < 8; ++e) vones[e] = (short)0x3F80;
    }

    for (int hh = 0; hh < 2; ++hh) {
        const int h = w + hh * 4;
        const int hoff = h * 32;

        bf16x8 kf[4], qf[4];
        #pragma unroll
        for (int i = 0; i < 4; ++i) {
            int t = 16 * i + fr;
            if (CROSS && t > 48) t = 48;
            kf[i] = *reinterpret_cast<const bf16x8*>(
                ksrc + (size_t)(krow0 + t) * KSTR + hoff + g * 8);
        }
        #pragma unroll
        for (int j = 0; j < 4; ++j)
            qf[j] = *reinterpret_cast<const bf16x8*>(
                qsrc + (size_t)(qrow0 + 16 * j + fr) * QSTR + hoff + g * 8);

        // stage V transposed: Vt[d][k'], pair-packed b32 writes
        #pragma unroll
        for (int t2 = 0; t2 < 2; ++t2) {
            const int task = t2 * 64 + l;
            const int rp = task >> 2, cg = task & 3;
            int r0 = 2 * rp, r1 = r0 + 1;
            if (CROSS) { if (r0 > 48) r0 = 48; if (r1 > 48) r1 = 48; }
            const uint4 a = *reinterpret_cast<const uint4*>(
                vsrc + (size_t)(krow0 + r0) * KSTR + hoff + cg * 8);
            const uint4 b = *reinterpret_cast<const uint4*>(
                vsrc + (size_t)(krow0 + r1) * KSTR + hoff + cg * 8);
            const uint ac[4] = {a.x, a.y, a.z, a.w};
            const uint bc[4] = {b.x, b.y, b.z, b.w};
            #pragma unroll
            for (int k = 0; k < 4; ++k) {
                uint lo = (ac[k] & 0xFFFFu) | (bc[k] << 16);
                uint hi = (ac[k] >> 16)     | (bc[k] & 0xFFFF0000u);
                *reinterpret_cast<uint*>(&Vt[cg * 8 + 2 * k][2 * rp])     = lo;
                *reinterpret_cast<uint*>(&Vt[cg * 8 + 2 * k + 1][2 * rp]) = hi;
            }
        }

        // S^T = K @ Q^T
        f32x4 st_[4][4];
        #pragma unroll
        for (int i = 0; i < 4; ++i)
            #pragma unroll
            for (int j = 0; j < 4; ++j) {
                f32x4 z = {};
                st_[i][j] = __builtin_amdgcn_mfma_f32_16x16x32_bf16(
                    kf[i], qf[j], z, 0, 0, 0);
            }
        if (CROSS) {
            // k' = 48 + 4g + r >= 49 -> mask (exp(-1e30*scale) = 0)
            #pragma unroll
            for (int j = 0; j < 4; ++j)
                #pragma unroll
                for (int r = 0; r < 4; ++r)
                    if (r > 0 || g > 0) st_[3][j][r] = -1e30f;
        }

        // P = exp(s * scale), unnormalized, packed straight to LDS
        #pragma unroll
        for (int j = 0; j < 4; ++j) {
            const int q = 16 * j + fr;
            #pragma unroll
            for (int i = 0; i < 4; ++i) {
                float p0 = __expf(st_[i][j][0] * 0.17677669529663689f);
                float p1 = __expf(st_[i][j][1] * 0.17677669529663689f);
                float p2 = __expf(st_[i][j][2] * 0.17677669529663689f);
                float p3 = __expf(st_[i][j][3] * 0.17677669529663689f);
                *reinterpret_cast<uint2*>(&P[q][16 * i + 4 * g]) =
                    make_uint2(f2b_pk(p0, p1), f2b_pk(p2, p3));
            }
        }

        // wave-local sync: P/Vt are per-wave; DS ops per-wave are in-order.
        asm volatile("s_waitcnt lgkmcnt(0)" ::: "memory");
        __builtin_amdgcn_sched_barrier(0);

        // O = P @ V ; osum = P @ ones (row-sums in col 0)
        f32x4 o[4][2] = {};
        f32x4 osum[4] = {};
        #pragma unroll
        for (int s = 0; s < 2; ++s) {
            bf16x8 pa[4], vb[2];
            #pragma unroll
            for (int i = 0; i < 4; ++i)
                pa[i] = *reinterpret_cast<const bf16x8*>(&P[16 * i + fr][32 * s + 8 * g]);
            #pragma unroll
            for (int j2 = 0; j2 < 2; ++j2)
                vb[j2] = *reinterpret_cast<const bf16x8*>(&Vt[16 * j2 + fr][32 * s + 8 * g]);
            #pragma unroll
            for (int i = 0; i < 4; ++i) {
                #pragma unroll
                for (int j2 = 0; j2 < 2; ++j2)
                    o[i][j2] = __builtin_amdgcn_mfma_f32_16x16x32_bf16(
                        pa[i], vb[j2], o[i][j2], 0, 0, 0);
                osum[i] = __builtin_amdgcn_mfma_f32_16x16x32_bf16(
                    pa[i], vones, osum[i], 0, 0, 0);
            }
        }

        // normalize O by row-sums (sum lives in col 0 -> lane (g<<4))
        #pragma unroll
        for (int i = 0; i < 4; ++i)
            #pragma unroll
            for (int r = 0; r < 4; ++r) {
                const float rsum = __shfl(osum[i][r], (l & 48));
                const float inv = 1.f / rsum;
                o[i][0][r] *= inv;
                o[i][1][r] *= inv;
            }

        __syncthreads();   // all waves done reading P -> safe to overlay Os

        #pragma unroll
        for (int i = 0; i < 4; ++i)
            #pragma unroll
            for (int j2 = 0; j2 < 2; ++j2)
                #pragma unroll
                for (int r = 0; r < 4; ++r)
                    Os[(16 * i + 4 * g + r) * 128 + w * 32 + 16 * j2 + fr] =
                        f2b(o[i][j2][r]);
        __syncthreads();   // Os complete

        #pragma unroll
        for (int it = 0; it < 4; ++it) {
            const int elem = (it * 256 + tid) * 8;
            const int lrow = elem >> 7, lcol = elem & 127;
            *reinterpret_cast<uint4*>(
                &out[(size_t)(qrow0 + lrow) * 256 + hh * 128 + lcol]) =
                *reinterpret_cast<const uint4*>(&Os[elem]);
        }
        __syncthreads();   // Os reads done -> next hh's P/Vt writes
    }
}

// ---------------------------------------------------------------------------
// st init (bf16 only): stb[b,s,d] = init_part_tokens[s,d] + part_id_emb[s>>6,d]
// ---------------------------------------------------------------------------
__global__ __launch_bounds__(256) void init_st(
    ushort* __restrict__ stb,
    const float* __restrict__ init_tokens, const float* __restrict__ pid_emb)
{
    int i = blockIdx.x * 256 + threadIdx.x;
    int c = i & 63;
    int s = (i >> 6) & 511;
    int p = s >> 6;
    float4 v = *reinterpret_cast<const float4*>(&init_tokens[s * 256 + c * 4]);
    float4 e = *reinterpret_cast<const float4*>(&pid_emb[p * 256 + c * 4]);
    v.x += e.x; v.y += e.y; v.z += e.z; v.w += e.w;
    *reinterpret_cast<uint2*>(&stb[(size_t)i * 4]) =
        make_uint2(f2b_pk(v.x, v.y), f2b_pk(v.z, v.w));
}

// ---------------------------------------------------------------------------
// Coords head (bf16 input): out[m,n] = stb[m,:].coord_w[n,:] + coord_b[n]
// ---------------------------------------------------------------------------
__global__ __launch_bounds__(256) void coord_head(
    const ushort* __restrict__ stb, const float* __restrict__ w,
    const float* __restrict__ b, float* __restrict__ out)
{
    const int row = blockIdx.x * 8 + (threadIdx.x >> 5);
    const int l   = threadIdx.x & 31;
    const ushort* x = stb + (size_t)row * 256 + l * 8;
    uint4 xv = *reinterpret_cast<const uint4*>(x);
    float xf[8];
    const uint xc[4] = {xv.x, xv.y, xv.z, xv.w};
    #pragma unroll
    for (int k = 0; k < 4; ++k) {
        xf[2*k]   = __uint_as_float(xc[k] << 16);
        xf[2*k+1] = __uint_as_float(xc[k] & 0xFFFF0000u);
    }
    float acc[3];
    #pragma unroll
    for (int n = 0; n < 3; ++n) {
        const float* wn = w + n * 256 + l * 8;
        float4 w0 = *reinterpret_cast<const float4*>(wn);
        float4 w1 = *reinterpret_cast<const float4*>(wn + 4);
        acc[n] = xf[0]*w0.x + xf[1]*w0.y + xf[2]*w0.z + xf[3]*w0.w
               + xf[4]*w1.x + xf[5]*w1.y + xf[6]*w1.z + xf[7]*w1.w;
    }
    #pragma unroll
    for (int o = 16; o; o >>= 1)
        #pragma unroll
        for (int n = 0; n < 3; ++n) acc[n] += __shfl_xor(acc[n], o);
    if (l == 0) {
        #pragma unroll
        for (int n = 0; n < 3; ++n) out[(size_t)row * 3 + n] = acc[n] + b[n];
    }
}

// ---------------------------------------------------------------------------
extern "C" void kernel_launch(void* const* d_in, const int* in_sizes, int n_in,
                              void* d_out, int out_size, void* d_ws, size_t ws_size,
                              hipStream_t stream)
{
    const float* feat             = (const float*)d_in[0];
    const float* img_proj_w      = (const float*)d_in[1];
    const float* img_proj_b      = (const float*)d_in[2];
    const float* init_part_tokens = (const float*)d_in[3];
    const float* part_id_emb     = (const float*)d_in[4];
    const float* local_in_w      = (const float*)d_in[5];
    const float* local_in_b      = (const float*)d_in[6];
    const float* local_out_w     = (const float*)d_in[7];
    const float* local_out_b     = (const float*)d_in[8];
    const float* cross_in_w      = (const float*)d_in[9];
    const float* cross_in_b      = (const float*)d_in[10];
    const float* cross_out_w     = (const float*)d_in[11];
    const float* cross_out_b     = (const float*)d_in[12];
    const float* norm1_w         = (const float*)d_in[13];
    const float* norm1_b         = (const float*)d_in[14];
    const float* norm2_w         = (const float*)d_in[15];
    const float* norm2_b         = (const float*)d_in[16];
    const float* coord_w         = (const float*)d_in[17];
    const float* coord_b         = (const float*)d_in[18];
    float* out = (float*)d_out;

    // Workspace layout (all bf16 activations)
    ushort* stb  = (ushort*)d_ws;                      // 32768*256 bf16 state
    ushort* big  = stb  + (size_t)M_ST * D_;           // 32768*768 bf16
    ushort* attn = big  + (size_t)M_ST * 3 * D_;       // 32768*256 bf16
    ushort* fbf  = attn + (size_t)M_ST * D_;           // 3136*512
    ushort* img  = fbf  + (size_t)M_IMG * 512;         // 3136*256
    ushort* kimg = img  + (size_t)M_IMG * D_;
    ushort* vimg = kimg + (size_t)M_IMG * D_;
    ushort* lw_in  = vimg  + (size_t)M_IMG * D_;
    ushort* lw_out = lw_in  + 768 * 256;
    ushort* cw_in  = lw_out + 256 * 256;
    ushort* cw_out = cw_in  + 768 * 256;
    ushort* iw     = cw_out + 256 * 256;

    // --- conversions (tiny) ---
    cvt_bf16x4<<<768*256/4/256, 256, 0, stream>>>((const float4*)local_in_w,  (uint2*)lw_in,  768*256/4);
    cvt_bf16x4<<<256*256/4/256, 256, 0, stream>>>((const float4*)local_out_w, (uint2*)lw_out, 256*256/4);
    cvt_bf16x4<<<768*256/4/256, 256, 0, stream>>>((const float4*)cross_in_w,  (uint2*)cw_in,  768*256/4);
    cvt_bf16x4<<<256*256/4/256, 256, 0, stream>>>((const float4*)cross_out_w, (uint2*)cw_out, 256*256/4);
    cvt_bf16x4<<<256*512/4/256, 256, 0, stream>>>((const float4*)img_proj_w,  (uint2*)iw,     256*512/4);
    cvt_bf16x4<<<(M_IMG*512/4 + 255)/256, 256, 0, stream>>>((const float4*)feat, (uint2*)fbf, M_IMG*512/4);

    // --- one-time precompute ---
    gemm_bf16<<<dim3((M_IMG+127)/128, 2), 256, 0, stream>>>(fbf, iw, img_proj_b, img, M_IMG, 256, 512);
    gemm_bf16<<<dim3((M_IMG+127)/128, 2), 256, 0, stream>>>(img, cw_in + 256*256, cross_in_b + 256, kimg, M_IMG, 256, 256);
    gemm_bf16<<<dim3((M_IMG+127)/128, 2), 256, 0, stream>>>(img, cw_in + 512*256, cross_in_b + 512, vimg, M_IMG, 256, 256);
    init_st<<<M_ST * D_ / 4 / 256, 256, 0, stream>>>(stb, init_part_tokens, part_id_emb);

    // --- 6 transformer blocks ---
    for (int i = 0; i < 6; ++i) {
        // local MHA
        gemm_bf16_big<<<dim3(M_ST/256, 6), 512, 0, stream>>>(stb, lw_in, local_in_b, big, 768, 256);
        attn_mfma<0><<<512, 256, 0, stream>>>(big, big + 256, big + 512, attn);
        gemm_ln<<<M_ST/64, 256, 0, stream>>>(attn, lw_out, local_out_b, stb,
                                             norm1_w + i*256, norm1_b + i*256);
        // cross MHA (K/V precomputed)
        gemm_bf16_big<<<dim3(M_ST/256, 2), 512, 0, stream>>>(stb, cw_in, cross_in_b, big, 256, 256);
        attn_mfma<1><<<512, 256, 0, stream>>>(big, kimg, vimg, attn);
        gemm_ln<<<M_ST/64, 256, 0, stream>>>(attn, cw_out, cross_out_b, stb,
                                             norm2_w + i*256, norm2_b + i*256);
    }

    // --- coords head ---
    coord_head<<<M_ST / 8, 256, 0, stream>>>(stb, coord_w, coord_b, out);
}

// Round 11
// 725.126 us; speedup vs baseline: 1.0371x; 1.0371x over previous
//
#include <hip/hip_runtime.h>
#include <hip/hip_bf16.h>

// PointCraft++: 6 transformer blocks (local MHA within 64-token parts +
// cross MHA to 49 image tokens) over a (64, 512, 256) state stream.
// Round 11: revert round-10 attn arithmetic (regression); instead cut attn
// barrier count 8->4 per block: both heads' O kept in registers, ONE combined
// 64x256 Os gather + coalesced store at the end. Numerics = round 9.

#define B_     64
#define P_     8
#define T_     64
#define S_     512
#define D_     256
#define H_     8
#define DH_    32
#define NIMG_  49
#define M_ST   32768
#define M_IMG  3136

#define AS1 __attribute__((address_space(1)))
#define AS3 __attribute__((address_space(3)))

typedef short bf16x8 __attribute__((ext_vector_type(8)));
typedef float f32x4  __attribute__((ext_vector_type(4)));

__device__ inline uint f2b_pk(float x, float y) {
    uint bx = __float_as_uint(x), by = __float_as_uint(y);
    bx = (bx + 0x7FFFu + ((bx >> 16) & 1u)) >> 16;
    by = (by + 0x7FFFu + ((by >> 16) & 1u)) >> 16;
    return bx | (by << 16);
}
__device__ inline ushort f2b(float x) {
    uint b = __float_as_uint(x);
    return (ushort)((b + 0x7FFFu + ((b >> 16) & 1u)) >> 16);
}
__device__ inline float b2f(ushort u) {
    return __uint_as_float(((uint)u) << 16);
}

// ---------------------------------------------------------------------------
// fp32 -> bf16 conversion (weights + feat, one-time per launch)
// ---------------------------------------------------------------------------
__global__ __launch_bounds__(256) void cvt_bf16x4(
    const float4* __restrict__ in, uint2* __restrict__ out, int n4)
{
    int i = blockIdx.x * 256 + threadIdx.x;
    if (i < n4) {
        float4 v = in[i];
        out[i] = make_uint2(f2b_pk(v.x, v.y), f2b_pk(v.z, v.w));
    }
}

// ---------------------------------------------------------------------------
// MFMA GEMM (small): 128x128 tile, BK=32, 4 waves. Used for M_IMG precompute.
// ---------------------------------------------------------------------------
__global__ __launch_bounds__(256) void gemm_bf16(
    const ushort* __restrict__ A,
    const ushort* __restrict__ W,
    const float*  __restrict__ bias,
    ushort*       __restrict__ C,
    int M, int N, int K)
{
    __shared__ ushort smem[128 * 128];
    ushort* Asm = smem;
    ushort* Bsm = smem + 4096;

    const int tid  = threadIdx.x;
    const int lane = tid & 63;
    const int wave = tid >> 6;
    const int wr = wave >> 1, wc = wave & 1;
    const int row0 = blockIdx.x * 128, col0 = blockIdx.y * 128;

    f32x4 acc[4][4] = {};

    const int skc = (tid & 3) * 8;
    const int sr0 = tid >> 2;
    const int fr  = lane & 15;
    const int g   = lane >> 4;

    for (int k0 = 0; k0 < K; k0 += 32) {
        #pragma unroll
        for (int i = 0; i < 2; ++i) {
            const int r = sr0 + i * 64;
            const int e = (tid + i * 256) * 8;
            int ra = row0 + r; if (ra >= M) ra = M - 1;
            __builtin_amdgcn_global_load_lds(
                (const AS1 void*)(A + (size_t)ra * K + k0 + skc),
                (AS3 void*)&Asm[e], 16, 0, 0);
            __builtin_amdgcn_global_load_lds(
                (const AS1 void*)(W + (size_t)(col0 + r) * K + k0 + skc),
                (AS3 void*)&Bsm[e], 16, 0, 0);
        }
        __syncthreads();

        bf16x8 af[4], bf[4];
        #pragma unroll
        for (int i = 0; i < 4; ++i)
            af[i] = *reinterpret_cast<const bf16x8*>(&Asm[(wr * 64 + i * 16 + fr) * 32 + g * 8]);
        #pragma unroll
        for (int j = 0; j < 4; ++j)
            bf[j] = *reinterpret_cast<const bf16x8*>(&Bsm[(wc * 64 + j * 16 + fr) * 32 + g * 8]);
        #pragma unroll
        for (int i = 0; i < 4; ++i)
            #pragma unroll
            for (int j = 0; j < 4; ++j)
                acc[i][j] = __builtin_amdgcn_mfma_f32_16x16x32_bf16(
                    af[i], bf[j], acc[i][j], 0, 0, 0);
        __syncthreads();
    }

    float bn[4];
    #pragma unroll
    for (int j = 0; j < 4; ++j) bn[j] = bias[col0 + wc * 64 + j * 16 + fr];

    #pragma unroll
    for (int i = 0; i < 4; ++i)
        #pragma unroll
        for (int j = 0; j < 4; ++j)
            #pragma unroll
            for (int r = 0; r < 4; ++r)
                smem[(wr * 64 + i * 16 + g * 4 + r) * 128 + wc * 64 + j * 16 + fr] =
                    f2b(acc[i][j][r] + bn[j]);
    __syncthreads();

    #pragma unroll
    for (int it = 0; it < 8; ++it) {
        const int elem = (it * 256 + tid) * 8;
        const int lrow = elem >> 7, lcol = elem & 127;
        const int m = row0 + lrow;
        if (m < M)
            *reinterpret_cast<uint4*>(&C[(size_t)m * N + col0 + lcol]) =
                *reinterpret_cast<const uint4*>(&smem[elem]);
    }
}

// ---------------------------------------------------------------------------
// MFMA GEMM (big): BM=256, BN=128, BK=32, 512 threads = 8 waves (4x2).
// For M % 256 == 0 (M_ST projections). grid = (M/256, N/128).
// ---------------------------------------------------------------------------
__global__ __launch_bounds__(512, 4) void gemm_bf16_big(
    const ushort* __restrict__ A,
    const ushort* __restrict__ W,
    const float*  __restrict__ bias,
    ushort*       __restrict__ C,
    int N, int K)
{
    __shared__ ushort smem[16384];       // As [0,8192); Bs [8192,12288)
    ushort* Asm = smem;
    ushort* Bsm = smem + 8192;

    const int tid  = threadIdx.x;
    const int lane = tid & 63;
    const int wave = tid >> 6;           // 0..7
    const int wr = wave >> 1, wc = wave & 1;
    const int row0 = blockIdx.x * 256, col0 = blockIdx.y * 128;

    f32x4 acc[4][4] = {};
    const int skc = (tid & 3) * 8;
    const int sr0 = tid >> 2;            // 0..127
    const int fr  = lane & 15;
    const int g   = lane >> 4;

    for (int k0 = 0; k0 < K; k0 += 32) {
        #pragma unroll
        for (int i = 0; i < 2; ++i) {
            const int r = sr0 + i * 128;             // 0..255
            __builtin_amdgcn_global_load_lds(
                (const AS1 void*)(A + (size_t)(row0 + r) * K + k0 + skc),
                (AS3 void*)&Asm[(tid + i * 512) * 8], 16, 0, 0);
        }
        __builtin_amdgcn_global_load_lds(
            (const AS1 void*)(W + (size_t)(col0 + sr0) * K + k0 + skc),
            (AS3 void*)&Bsm[tid * 8], 16, 0, 0);
        __syncthreads();

        bf16x8 af[4], bf[4];
        #pragma unroll
        for (int i = 0; i < 4; ++i)
            af[i] = *reinterpret_cast<const bf16x8*>(&Asm[(wr * 64 + i * 16 + fr) * 32 + g * 8]);
        #pragma unroll
        for (int j = 0; j < 4; ++j)
            bf[j] = *reinterpret_cast<const bf16x8*>(&Bsm[(wc * 64 + j * 16 + fr) * 32 + g * 8]);
        #pragma unroll
        for (int i = 0; i < 4; ++i)
            #pragma unroll
            for (int j = 0; j < 4; ++j)
                acc[i][j] = __builtin_amdgcn_mfma_f32_16x16x32_bf16(
                    af[i], bf[j], acc[i][j], 0, 0, 0);
        __syncthreads();
    }

    float bn[4];
    #pragma unroll
    for (int j = 0; j < 4; ++j) bn[j] = bias[col0 + wc * 64 + j * 16 + fr];

    // epilogue: two 128x128 halves through LDS, coalesced 16B stores
    #pragma unroll
    for (int h2 = 0; h2 < 2; ++h2) {
        if ((wr >> 1) == h2) {
            const int lwr = wr & 1;
            #pragma unroll
            for (int i = 0; i < 4; ++i)
                #pragma unroll
                for (int j = 0; j < 4; ++j)
                    #pragma unroll
                    for (int r = 0; r < 4; ++r)
                        smem[(lwr * 64 + i * 16 + g * 4 + r) * 128 + wc * 64 + j * 16 + fr] =
                            f2b(acc[i][j][r] + bn[j]);
        }
        __syncthreads();
        #pragma unroll
        for (int it = 0; it < 4; ++it) {
            const int elem = (it * 512 + tid) * 8;
            const int lrow = elem >> 7, lcol = elem & 127;
            *reinterpret_cast<uint4*>(
                &C[(size_t)(row0 + h2 * 128 + lrow) * N + col0 + lcol]) =
                *reinterpret_cast<const uint4*>(&smem[elem]);
        }
        __syncthreads();
    }
}

// ---------------------------------------------------------------------------
// Fused out-proj GEMM + residual + LayerNorm, bf16 state (round-9 verbatim).
// BM=64, BN=256, BK=32, 256 threads = 4 waves. Grid = M/64 = 512.
// ---------------------------------------------------------------------------
__global__ __launch_bounds__(256) void gemm_ln(
    const ushort* __restrict__ A,
    const ushort* __restrict__ W,
    const float*  __restrict__ bias,
    ushort*       __restrict__ stb,
    const float*  __restrict__ lnw,
    const float*  __restrict__ lnb)
{
    __shared__ ushort As[64 * 32];
    __shared__ ushort Bs[256 * 32];
    __shared__ ushort Cs[64 * 256];
    __shared__ float  redS[64][4];
    __shared__ float  redS2[64][4];

    const int tid  = threadIdx.x;
    const int lane = tid & 63;
    const int wc   = tid >> 6;
    const int fr = lane & 15, g = lane >> 4;
    const int row0 = blockIdx.x * 64;

    f32x4 acc[4][4] = {};
    const int skc = (tid & 3) * 8;
    const int sr  = tid >> 2;

    for (int k0 = 0; k0 < 256; k0 += 32) {
        __builtin_amdgcn_global_load_lds(
            (const AS1 void*)(A + (size_t)(row0 + sr) * 256 + k0 + skc),
            (AS3 void*)&As[tid * 8], 16, 0, 0);
        #pragma unroll
        for (int q = 0; q < 4; ++q)
            __builtin_amdgcn_global_load_lds(
                (const AS1 void*)(W + (size_t)(sr + q * 64) * 256 + k0 + skc),
                (AS3 void*)&Bs[(tid + q * 256) * 8], 16, 0, 0);
        __syncthreads();

        bf16x8 af[4], bf[4];
        #pragma unroll
        for (int i = 0; i < 4; ++i)
            af[i] = *reinterpret_cast<const bf16x8*>(&As[(i * 16 + fr) * 32 + g * 8]);
        #pragma unroll
        for (int j = 0; j < 4; ++j)
            bf[j] = *reinterpret_cast<const bf16x8*>(&Bs[(wc * 64 + j * 16 + fr) * 32 + g * 8]);
        #pragma unroll
        for (int i = 0; i < 4; ++i)
            #pragma unroll
            for (int j = 0; j < 4; ++j)
                acc[i][j] = __builtin_amdgcn_mfma_f32_16x16x32_bf16(
                    af[i], bf[j], acc[i][j], 0, 0, 0);
        __syncthreads();
    }

    int   col[4]; float bv[4], wv[4], lb[4];
    #pragma unroll
    for (int j = 0; j < 4; ++j) {
        col[j] = wc * 64 + j * 16 + fr;
        bv[j]  = bias[col[j]];
        wv[j]  = lnw[col[j]];
        lb[j]  = lnb[col[j]];
    }

    // pass 1: x = acc + bias + stb(bf16); per-row partial sums -> LDS
    #pragma unroll
    for (int i = 0; i < 4; ++i)
        #pragma unroll
        for (int r = 0; r < 4; ++r) {
            const int rl = i * 16 + g * 4 + r;
            const size_t rb = (size_t)(row0 + rl) * 256;
            float s = 0.f, s2 = 0.f;
            #pragma unroll
            for (int j = 0; j < 4; ++j) {
                float x = acc[i][j][r] + bv[j] + b2f(stb[rb + col[j]]);
                acc[i][j][r] = x;
                s += x; s2 += x * x;
            }
            #pragma unroll
            for (int o = 1; o < 16; o <<= 1) {
                s  += __shfl_xor(s, o);
                s2 += __shfl_xor(s2, o);
            }
            if (fr == 0) { redS[rl][wc] = s; redS2[rl][wc] = s2; }
        }
    __syncthreads();

    // pass 2: normalize -> Cs (bf16)
    #pragma unroll
    for (int i = 0; i < 4; ++i)
        #pragma unroll
        for (int r = 0; r < 4; ++r) {
            const int rl = i * 16 + g * 4 + r;
            const float ts  = redS[rl][0] + redS[rl][1] + redS[rl][2] + redS[rl][3];
            const float ts2 = redS2[rl][0] + redS2[rl][1] + redS2[rl][2] + redS2[rl][3];
            const float mean = ts * (1.f / 256.f);
            const float var  = ts2 * (1.f / 256.f) - mean * mean;
            const float rs   = rsqrtf(var + 1e-5f);
            #pragma unroll
            for (int j = 0; j < 4; ++j) {
                const float y = (acc[i][j][r] - mean) * rs * wv[j] + lb[j];
                Cs[rl * 256 + col[j]] = f2b(y);
            }
        }
    __syncthreads();

    // coalesced stb store (64 x 256)
    #pragma unroll
    for (int it = 0; it < 8; ++it) {
        const int elem = (it * 256 + tid) * 8;
        const int rl = elem >> 8, c = elem & 255;
        *reinterpret_cast<uint4*>(&stb[(size_t)(row0 + rl) * 256 + c]) =
            *reinterpret_cast<const uint4*>(&Cs[elem]);
    }
}

// ---------------------------------------------------------------------------
// Fused MFMA attention. Grid 512, 4 waves, wave w handles heads {w, w+4}.
// Swapped QK^T; V^T staging; softmax with max-sub (round-9 numerics).
// Both heads' O tiles kept in registers; ONE combined 64x256 Os gather +
// coalesced store at the end. Barriers per block: 4 (was 8).
// Os (32 KB) overlays P_lds (36 KB).
// ---------------------------------------------------------------------------
template<int CROSS>
__global__ __launch_bounds__(256) void attn_mfma(
    const ushort* __restrict__ qsrc,
    const ushort* __restrict__ ksrc,
    const ushort* __restrict__ vsrc,
    ushort* __restrict__ out)
{
    constexpr int QSTR = CROSS ? 256 : 768;
    constexpr int KSTR = CROSS ? 256 : 768;

    const int bid = blockIdx.x;
    int qrow0, krow0;
    if (CROSS) { qrow0 = (bid >> 3) * 512 + (bid & 7) * 64; krow0 = (bid >> 3) * 49; }
    else       { qrow0 = bid * 64; krow0 = bid * 64; }

    __shared__ ushort P_lds[4][64][72];   // 36 KB; Os (64x256 = 32 KB) overlays
    __shared__ ushort Vt_lds[4][32][72];  // 18 KB
    ushort* Os = &P_lds[0][0][0];

    const int tid = threadIdx.x;
    const int w = tid >> 6, l = tid & 63;
    const int fr = l & 15, g = l >> 4;
    ushort (*P)[72]  = P_lds[w];
    ushort (*Vt)[72] = Vt_lds[w];

    f32x4 o2[2][4][2] = {};

    #pragma unroll
    for (int hh = 0; hh < 2; ++hh) {
        const int h = w + hh * 4;
        const int hoff = h * 32;

        bf16x8 kf[4], qf[4];
        #pragma unroll
        for (int i = 0; i < 4; ++i) {
            int t = 16 * i + fr;
            if (CROSS && t > 48) t = 48;
            kf[i] = *reinterpret_cast<const bf16x8*>(
                ksrc + (size_t)(krow0 + t) * KSTR + hoff + g * 8);
        }
        #pragma unroll
        for (int j = 0; j < 4; ++j)
            qf[j] = *reinterpret_cast<const bf16x8*>(
                qsrc + (size_t)(qrow0 + 16 * j + fr) * QSTR + hoff + g * 8);

        // stage V transposed: Vt[d][k'], pair-packed b32 writes.
        // (hh=1 overwrite of this wave's own Vt/P slice is a wave-local WAR:
        //  per-wave DS ops are in-order, and no other wave touches this slice)
        #pragma unroll
        for (int t2 = 0; t2 < 2; ++t2) {
            const int task = t2 * 64 + l;
            const int rp = task >> 2, cg = task & 3;
            int r0 = 2 * rp, r1 = r0 + 1;
            if (CROSS) { if (r0 > 48) r0 = 48; if (r1 > 48) r1 = 48; }
            const uint4 a = *reinterpret_cast<const uint4*>(
                vsrc + (size_t)(krow0 + r0) * KSTR + hoff + cg * 8);
            const uint4 b = *reinterpret_cast<const uint4*>(
                vsrc + (size_t)(krow0 + r1) * KSTR + hoff + cg * 8);
            const uint ac[4] = {a.x, a.y, a.z, a.w};
            const uint bc[4] = {b.x, b.y, b.z, b.w};
            #pragma unroll
            for (int k = 0; k < 4; ++k) {
                uint lo = (ac[k] & 0xFFFFu) | (bc[k] << 16);
                uint hi = (ac[k] >> 16)     | (bc[k] & 0xFFFF0000u);
                *reinterpret_cast<uint*>(&Vt[cg * 8 + 2 * k][2 * rp])     = lo;
                *reinterpret_cast<uint*>(&Vt[cg * 8 + 2 * k + 1][2 * rp]) = hi;
            }
        }

        // S^T = K @ Q^T
        f32x4 st_[4][4];
        #pragma unroll
        for (int i = 0; i < 4; ++i)
            #pragma unroll
            for (int j = 0; j < 4; ++j) {
                f32x4 z = {};
                st_[i][j] = __builtin_amdgcn_mfma_f32_16x16x32_bf16(
                    kf[i], qf[j], z, 0, 0, 0);
                st_[i][j] *= 0.17677669529663689f;
            }
        if (CROSS) {
            #pragma unroll
            for (int j = 0; j < 4; ++j)
                #pragma unroll
                for (int r = 0; r < 4; ++r)
                    if (r > 0 || g > 0) st_[3][j][r] = -1e30f;
        }

        // softmax per q-column (max-sub, normalized), pack P^T
        #pragma unroll
        for (int j = 0; j < 4; ++j) {
            float mx = -1e30f;
            #pragma unroll
            for (int i = 0; i < 4; ++i)
                #pragma unroll
                for (int r = 0; r < 4; ++r) mx = fmaxf(mx, st_[i][j][r]);
            mx = fmaxf(mx, __shfl_xor(mx, 16));
            mx = fmaxf(mx, __shfl_xor(mx, 32));
            float sm = 0.f;
            #pragma unroll
            for (int i = 0; i < 4; ++i)
                #pragma unroll
                for (int r = 0; r < 4; ++r) {
                    float p = __expf(st_[i][j][r] - mx);
                    st_[i][j][r] = p;
                    sm += p;
                }
            sm += __shfl_xor(sm, 16);
            sm += __shfl_xor(sm, 32);
            const float inv = 1.f / sm;
            const int q = 16 * j + fr;
            #pragma unroll
            for (int i = 0; i < 4; ++i) {
                uint lo = f2b_pk(st_[i][j][0] * inv, st_[i][j][1] * inv);
                uint hi = f2b_pk(st_[i][j][2] * inv, st_[i][j][3] * inv);
                *reinterpret_cast<uint2*>(&P[q][16 * i + 4 * g]) = make_uint2(lo, hi);
            }
        }

        __syncthreads();   // P/Vt visible (barrier 1 & 2)

        // O = P @ V  -> o2[hh]
        #pragma unroll
        for (int s = 0; s < 2; ++s) {
            bf16x8 pa[4], vb[2];
            #pragma unroll
            for (int i = 0; i < 4; ++i)
                pa[i] = *reinterpret_cast<const bf16x8*>(&P[16 * i + fr][32 * s + 8 * g]);
            #pragma unroll
            for (int j2 = 0; j2 < 2; ++j2)
                vb[j2] = *reinterpret_cast<const bf16x8*>(&Vt[16 * j2 + fr][32 * s + 8 * g]);
            #pragma unroll
            for (int i = 0; i < 4; ++i)
                #pragma unroll
                for (int j2 = 0; j2 < 2; ++j2)
                    o2[hh][i][j2] = __builtin_amdgcn_mfma_f32_16x16x32_bf16(
                        pa[i], vb[j2], o2[hh][i][j2], 0, 0, 0);
        }
    }

    __syncthreads();   // all waves' PV reads done -> safe to overlay Os (b.3)

    // gather both heads: wave w owns cols {w*32..w*32+31} and {128+w*32..}
    #pragma unroll
    for (int hh = 0; hh < 2; ++hh)
        #pragma unroll
        for (int i = 0; i < 4; ++i)
            #pragma unroll
            for (int j2 = 0; j2 < 2; ++j2)
                #pragma unroll
                for (int r = 0; r < 4; ++r)
                    Os[(16 * i + 4 * g + r) * 256 + hh * 128 + w * 32 + 16 * j2 + fr] =
                        f2b(o2[hh][i][j2][r]);
    __syncthreads();   // Os complete (barrier 4)

    // coalesced store: 64 rows x 256 cols (512 B per row)
    #pragma unroll
    for (int it = 0; it < 8; ++it) {
        const int elem = (it * 256 + tid) * 8;
        const int lrow = elem >> 8, lcol = elem & 255;
        *reinterpret_cast<uint4*>(&out[(size_t)(qrow0 + lrow) * 256 + lcol]) =
            *reinterpret_cast<const uint4*>(&Os[elem]);
    }
}

// ---------------------------------------------------------------------------
// st init (bf16 only): stb[b,s,d] = init_part_tokens[s,d] + part_id_emb[s>>6,d]
// ---------------------------------------------------------------------------
__global__ __launch_bounds__(256) void init_st(
    ushort* __restrict__ stb,
    const float* __restrict__ init_tokens, const float* __restrict__ pid_emb)
{
    int i = blockIdx.x * 256 + threadIdx.x;
    int c = i & 63;
    int s = (i >> 6) & 511;
    int p = s >> 6;
    float4 v = *reinterpret_cast<const float4*>(&init_tokens[s * 256 + c * 4]);
    float4 e = *reinterpret_cast<const float4*>(&pid_emb[p * 256 + c * 4]);
    v.x += e.x; v.y += e.y; v.z += e.z; v.w += e.w;
    *reinterpret_cast<uint2*>(&stb[(size_t)i * 4]) =
        make_uint2(f2b_pk(v.x, v.y), f2b_pk(v.z, v.w));
}

// ---------------------------------------------------------------------------
// Coords head (bf16 input): out[m,n] = stb[m,:].coord_w[n,:] + coord_b[n]
// ---------------------------------------------------------------------------
__global__ __launch_bounds__(256) void coord_head(
    const ushort* __restrict__ stb, const float* __restrict__ w,
    const float* __restrict__ b, float* __restrict__ out)
{
    const int row = blockIdx.x * 8 + (threadIdx.x >> 5);
    const int l   = threadIdx.x & 31;
    const ushort* x = stb + (size_t)row * 256 + l * 8;
    uint4 xv = *reinterpret_cast<const uint4*>(x);
    float xf[8];
    const uint xc[4] = {xv.x, xv.y, xv.z, xv.w};
    #pragma unroll
    for (int k = 0; k < 4; ++k) {
        xf[2*k]   = __uint_as_float(xc[k] << 16);
        xf[2*k+1] = __uint_as_float(xc[k] & 0xFFFF0000u);
    }
    float acc[3];
    #pragma unroll
    for (int n = 0; n < 3; ++n) {
        const float* wn = w + n * 256 + l * 8;
        float4 w0 = *reinterpret_cast<const float4*>(wn);
        float4 w1 = *reinterpret_cast<const float4*>(wn + 4);
        acc[n] = xf[0]*w0.x + xf[1]*w0.y + xf[2]*w0.z + xf[3]*w0.w
               + xf[4]*w1.x + xf[5]*w1.y + xf[6]*w1.z + xf[7]*w1.w;
    }
    #pragma unroll
    for (int o = 16; o; o >>= 1)
        #pragma unroll
        for (int n = 0; n < 3; ++n) acc[n] += __shfl_xor(acc[n], o);
    if (l == 0) {
        #pragma unroll
        for (int n = 0; n < 3; ++n) out[(size_t)row * 3 + n] = acc[n] + b[n];
    }
}

// ---------------------------------------------------------------------------
extern "C" void kernel_launch(void* const* d_in, const int* in_sizes, int n_in,
                              void* d_out, int out_size, void* d_ws, size_t ws_size,
                              hipStream_t stream)
{
    const float* feat             = (const float*)d_in[0];
    const float* img_proj_w      = (const float*)d_in[1];
    const float* img_proj_b      = (const float*)d_in[2];
    const float* init_part_tokens = (const float*)d_in[3];
    const float* part_id_emb     = (const float*)d_in[4];
    const float* local_in_w      = (const float*)d_in[5];
    const float* local_in_b      = (const float*)d_in[6];
    const float* local_out_w     = (const float*)d_in[7];
    const float* local_out_b     = (const float*)d_in[8];
    const float* cross_in_w      = (const float*)d_in[9];
    const float* cross_in_b      = (const float*)d_in[10];
    const float* cross_out_w     = (const float*)d_in[11];
    const float* cross_out_b     = (const float*)d_in[12];
    const float* norm1_w         = (const float*)d_in[13];
    const float* norm1_b         = (const float*)d_in[14];
    const float* norm2_w         = (const float*)d_in[15];
    const float* norm2_b         = (const float*)d_in[16];
    const float* coord_w         = (const float*)d_in[17];
    const float* coord_b         = (const float*)d_in[18];
    float* out = (float*)d_out;

    // Workspace layout (all bf16 activations)
    ushort* stb  = (ushort*)d_ws;                      // 32768*256 bf16 state
    ushort* big  = stb  + (size_t)M_ST * D_;           // 32768*768 bf16
    ushort* attn = big  + (size_t)M_ST * 3 * D_;       // 32768*256 bf16
    ushort* fbf  = attn + (size_t)M_ST * D_;           // 3136*512
    ushort* img  = fbf  + (size_t)M_IMG * 512;         // 3136*256
    ushort* kimg = img  + (size_t)M_IMG * D_;
    ushort* vimg = kimg + (size_t)M_IMG * D_;
    ushort* lw_in  = vimg  + (size_t)M_IMG * D_;
    ushort* lw_out = lw_in  + 768 * 256;
    ushort* cw_in  = lw_out + 256 * 256;
    ushort* cw_out = cw_in  + 768 * 256;
    ushort* iw     = cw_out + 256 * 256;

    // --- conversions (tiny) ---
    cvt_bf16x4<<<768*256/4/256, 256, 0, stream>>>((const float4*)local_in_w,  (uint2*)lw_in,  768*256/4);
    cvt_bf16x4<<<256*256/4/256, 256, 0, stream>>>((const float4*)local_out_w, (uint2*)lw_out, 256*256/4);
    cvt_bf16x4<<<768*256/4/256, 256, 0, stream>>>((const float4*)cross_in_w,  (uint2*)cw_in,  768*256/4);
    cvt_bf16x4<<<256*256/4/256, 256, 0, stream>>>((const float4*)cross_out_w, (uint2*)cw_out, 256*256/4);
    cvt_bf16x4<<<256*512/4/256, 256, 0, stream>>>((const float4*)img_proj_w,  (uint2*)iw,     256*512/4);
    cvt_bf16x4<<<(M_IMG*512/4 + 255)/256, 256, 0, stream>>>((const float4*)feat, (uint2*)fbf, M_IMG*512/4);

    // --- one-time precompute ---
    gemm_bf16<<<dim3((M_IMG+127)/128, 2), 256, 0, stream>>>(fbf, iw, img_proj_b, img, M_IMG, 256, 512);
    gemm_bf16<<<dim3((M_IMG+127)/128, 2), 256, 0, stream>>>(img, cw_in + 256*256, cross_in_b + 256, kimg, M_IMG, 256, 256);
    gemm_bf16<<<dim3((M_IMG+127)/128, 2), 256, 0, stream>>>(img, cw_in + 512*256, cross_in_b + 512, vimg, M_IMG, 256, 256);
    init_st<<<M_ST * D_ / 4 / 256, 256, 0, stream>>>(stb, init_part_tokens, part_id_emb);

    // --- 6 transformer blocks ---
    for (int i = 0; i < 6; ++i) {
        // local MHA
        gemm_bf16_big<<<dim3(M_ST/256, 6), 512, 0, stream>>>(stb, lw_in, local_in_b, big, 768, 256);
        attn_mfma<0><<<512, 256, 0, stream>>>(big, big + 256, big + 512, attn);
        gemm_ln<<<M_ST/64, 256, 0, stream>>>(attn, lw_out, local_out_b, stb,
                                             norm1_w + i*256, norm1_b + i*256);
        // cross MHA (K/V precomputed)
        gemm_bf16_big<<<dim3(M_ST/256, 2), 512, 0, stream>>>(stb, cw_in, cross_in_b, big, 256, 256);
        attn_mfma<1><<<512, 256, 0, stream>>>(big, kimg, vimg, attn);
        gemm_ln<<<M_ST/64, 256, 0, stream>>>(attn, cw_out, cross_out_b, stb,
                                             norm2_w + i*256, norm2_b + i*256);
    }

    // --- coords head ---
    coord_head<<<M_ST / 8, 256, 0, stream>>>(stb, coord_w, coord_b, out);
}

// Round 12
// 659.762 us; speedup vs baseline: 1.1398x; 1.0991x over previous
//
#include <hip/hip_runtime.h>
#include <hip/hip_bf16.h>

// PointCraft++: 6 transformer blocks (local MHA within 64-token parts +
// cross MHA to 49 image tokens) over a (64, 512, 256) state stream.
// Round 12: fuse attention + out-proj + residual + LayerNorm into one kernel
// (attn_oln). Phase A = round-11 attention (identical numerics); phase B =
// round-9 gemm_ln loop with A read from the LDS-resident Os tile (stride 264).
// LDS overlays: Bs(16K) on dead Vt(18K), Os(33.8K) on dead P(36K) -> 56 KB.
// kimg/vimg precompute merged into one N=512 GEMM (kv, KSTR=512).

#define B_     64
#define P_     8
#define T_     64
#define S_     512
#define D_     256
#define H_     8
#define DH_    32
#define NIMG_  49
#define M_ST   32768
#define M_IMG  3136
#define OSTR   264

#define AS1 __attribute__((address_space(1)))
#define AS3 __attribute__((address_space(3)))

typedef short bf16x8 __attribute__((ext_vector_type(8)));
typedef float f32x4  __attribute__((ext_vector_type(4)));

__device__ inline uint f2b_pk(float x, float y) {
    uint bx = __float_as_uint(x), by = __float_as_uint(y);
    bx = (bx + 0x7FFFu + ((bx >> 16) & 1u)) >> 16;
    by = (by + 0x7FFFu + ((by >> 16) & 1u)) >> 16;
    return bx | (by << 16);
}
__device__ inline ushort f2b(float x) {
    uint b = __float_as_uint(x);
    return (ushort)((b + 0x7FFFu + ((b >> 16) & 1u)) >> 16);
}
__device__ inline float b2f(ushort u) {
    return __uint_as_float(((uint)u) << 16);
}

// ---------------------------------------------------------------------------
// fp32 -> bf16 conversion (weights + feat, one-time per launch)
// ---------------------------------------------------------------------------
__global__ __launch_bounds__(256) void cvt_bf16x4(
    const float4* __restrict__ in, uint2* __restrict__ out, int n4)
{
    int i = blockIdx.x * 256 + threadIdx.x;
    if (i < n4) {
        float4 v = in[i];
        out[i] = make_uint2(f2b_pk(v.x, v.y), f2b_pk(v.z, v.w));
    }
}

// ---------------------------------------------------------------------------
// MFMA GEMM (small): 128x128 tile, BK=32, 4 waves. Used for M_IMG precompute.
// ---------------------------------------------------------------------------
__global__ __launch_bounds__(256) void gemm_bf16(
    const ushort* __restrict__ A,
    const ushort* __restrict__ W,
    const float*  __restrict__ bias,
    ushort*       __restrict__ C,
    int M, int N, int K)
{
    __shared__ ushort smem[128 * 128];
    ushort* Asm = smem;
    ushort* Bsm = smem + 4096;

    const int tid  = threadIdx.x;
    const int lane = tid & 63;
    const int wave = tid >> 6;
    const int wr = wave >> 1, wc = wave & 1;
    const int row0 = blockIdx.x * 128, col0 = blockIdx.y * 128;

    f32x4 acc[4][4] = {};

    const int skc = (tid & 3) * 8;
    const int sr0 = tid >> 2;
    const int fr  = lane & 15;
    const int g   = lane >> 4;

    for (int k0 = 0; k0 < K; k0 += 32) {
        #pragma unroll
        for (int i = 0; i < 2; ++i) {
            const int r = sr0 + i * 64;
            const int e = (tid + i * 256) * 8;
            int ra = row0 + r; if (ra >= M) ra = M - 1;
            __builtin_amdgcn_global_load_lds(
                (const AS1 void*)(A + (size_t)ra * K + k0 + skc),
                (AS3 void*)&Asm[e], 16, 0, 0);
            __builtin_amdgcn_global_load_lds(
                (const AS1 void*)(W + (size_t)(col0 + r) * K + k0 + skc),
                (AS3 void*)&Bsm[e], 16, 0, 0);
        }
        __syncthreads();

        bf16x8 af[4], bf[4];
        #pragma unroll
        for (int i = 0; i < 4; ++i)
            af[i] = *reinterpret_cast<const bf16x8*>(&Asm[(wr * 64 + i * 16 + fr) * 32 + g * 8]);
        #pragma unroll
        for (int j = 0; j < 4; ++j)
            bf[j] = *reinterpret_cast<const bf16x8*>(&Bsm[(wc * 64 + j * 16 + fr) * 32 + g * 8]);
        #pragma unroll
        for (int i = 0; i < 4; ++i)
            #pragma unroll
            for (int j = 0; j < 4; ++j)
                acc[i][j] = __builtin_amdgcn_mfma_f32_16x16x32_bf16(
                    af[i], bf[j], acc[i][j], 0, 0, 0);
        __syncthreads();
    }

    float bn[4];
    #pragma unroll
    for (int j = 0; j < 4; ++j) bn[j] = bias[col0 + wc * 64 + j * 16 + fr];

    #pragma unroll
    for (int i = 0; i < 4; ++i)
        #pragma unroll
        for (int j = 0; j < 4; ++j)
            #pragma unroll
            for (int r = 0; r < 4; ++r)
                smem[(wr * 64 + i * 16 + g * 4 + r) * 128 + wc * 64 + j * 16 + fr] =
                    f2b(acc[i][j][r] + bn[j]);
    __syncthreads();

    #pragma unroll
    for (int it = 0; it < 8; ++it) {
        const int elem = (it * 256 + tid) * 8;
        const int lrow = elem >> 7, lcol = elem & 127;
        const int m = row0 + lrow;
        if (m < M)
            *reinterpret_cast<uint4*>(&C[(size_t)m * N + col0 + lcol]) =
                *reinterpret_cast<const uint4*>(&smem[elem]);
    }
}

// ---------------------------------------------------------------------------
// MFMA GEMM (big): BM=256, BN=128, BK=32, 512 threads = 8 waves (4x2).
// For M % 256 == 0 (M_ST projections). grid = (M/256, N/128).
// ---------------------------------------------------------------------------
__global__ __launch_bounds__(512, 4) void gemm_bf16_big(
    const ushort* __restrict__ A,
    const ushort* __restrict__ W,
    const float*  __restrict__ bias,
    ushort*       __restrict__ C,
    int N, int K)
{
    __shared__ ushort smem[16384];       // As [0,8192); Bs [8192,12288)
    ushort* Asm = smem;
    ushort* Bsm = smem + 8192;

    const int tid  = threadIdx.x;
    const int lane = tid & 63;
    const int wave = tid >> 6;           // 0..7
    const int wr = wave >> 1, wc = wave & 1;
    const int row0 = blockIdx.x * 256, col0 = blockIdx.y * 128;

    f32x4 acc[4][4] = {};
    const int skc = (tid & 3) * 8;
    const int sr0 = tid >> 2;            // 0..127
    const int fr  = lane & 15;
    const int g   = lane >> 4;

    for (int k0 = 0; k0 < K; k0 += 32) {
        #pragma unroll
        for (int i = 0; i < 2; ++i) {
            const int r = sr0 + i * 128;             // 0..255
            __builtin_amdgcn_global_load_lds(
                (const AS1 void*)(A + (size_t)(row0 + r) * K + k0 + skc),
                (AS3 void*)&Asm[(tid + i * 512) * 8], 16, 0, 0);
        }
        __builtin_amdgcn_global_load_lds(
            (const AS1 void*)(W + (size_t)(col0 + sr0) * K + k0 + skc),
            (AS3 void*)&Bsm[tid * 8], 16, 0, 0);
        __syncthreads();

        bf16x8 af[4], bf[4];
        #pragma unroll
        for (int i = 0; i < 4; ++i)
            af[i] = *reinterpret_cast<const bf16x8*>(&Asm[(wr * 64 + i * 16 + fr) * 32 + g * 8]);
        #pragma unroll
        for (int j = 0; j < 4; ++j)
            bf[j] = *reinterpret_cast<const bf16x8*>(&Bsm[(wc * 64 + j * 16 + fr) * 32 + g * 8]);
        #pragma unroll
        for (int i = 0; i < 4; ++i)
            #pragma unroll
            for (int j = 0; j < 4; ++j)
                acc[i][j] = __builtin_amdgcn_mfma_f32_16x16x32_bf16(
                    af[i], bf[j], acc[i][j], 0, 0, 0);
        __syncthreads();
    }

    float bn[4];
    #pragma unroll
    for (int j = 0; j < 4; ++j) bn[j] = bias[col0 + wc * 64 + j * 16 + fr];

    // epilogue: two 128x128 halves through LDS, coalesced 16B stores
    #pragma unroll
    for (int h2 = 0; h2 < 2; ++h2) {
        if ((wr >> 1) == h2) {
            const int lwr = wr & 1;
            #pragma unroll
            for (int i = 0; i < 4; ++i)
                #pragma unroll
                for (int j = 0; j < 4; ++j)
                    #pragma unroll
                    for (int r = 0; r < 4; ++r)
                        smem[(lwr * 64 + i * 16 + g * 4 + r) * 128 + wc * 64 + j * 16 + fr] =
                            f2b(acc[i][j][r] + bn[j]);
        }
        __syncthreads();
        #pragma unroll
        for (int it = 0; it < 4; ++it) {
            const int elem = (it * 512 + tid) * 8;
            const int lrow = elem >> 7, lcol = elem & 127;
            *reinterpret_cast<uint4*>(
                &C[(size_t)(row0 + h2 * 128 + lrow) * N + col0 + lcol]) =
                *reinterpret_cast<const uint4*>(&smem[elem]);
        }
        __syncthreads();
    }
}

// ---------------------------------------------------------------------------
// FUSED attention + out-proj + residual + LayerNorm.
// Grid 512, 256 thr, 4 waves; wave w handles heads {w, w+4}.
// Phase A (= round-11 attn): swapped QK^T, V^T staging, softmax w/ max-sub,
//   both heads' O in registers, ONE Os gather (padded stride 264).
// Phase B (= round-9 gemm_ln): x = Os @ W^T + bias + stb; stb = LN(x).
//   A-operand read from LDS Os; W staged in Bs (overlays dead Vt).
// LDS: P/Os 36K + Vt/Bs 18K + red 2K = 56 KB -> 2 blocks/CU.
// ---------------------------------------------------------------------------
template<int CROSS>
__global__ __launch_bounds__(256) void attn_oln(
    const ushort* __restrict__ qsrc,
    const ushort* __restrict__ ksrc,
    const ushort* __restrict__ vsrc,
    const ushort* __restrict__ W,
    const float*  __restrict__ bias,
    ushort*       __restrict__ stb,
    const float*  __restrict__ lnw,
    const float*  __restrict__ lnb)
{
    constexpr int QSTR = CROSS ? 256 : 768;
    constexpr int KSTR = CROSS ? 512 : 768;   // cross: combined kv buffer

    const int bid = blockIdx.x;
    int qrow0, krow0;
    if (CROSS) { qrow0 = (bid >> 3) * 512 + (bid & 7) * 64; krow0 = (bid >> 3) * 49; }
    else       { qrow0 = bid * 64; krow0 = bid * 64; }

    __shared__ ushort P_lds[4][64][72];   // 36 KB; Os (64 x 264 = 33.8 KB) overlays
    __shared__ ushort Vt_lds[4][32][72];  // 18 KB; Bs (256 x 32 = 16 KB) overlays
    __shared__ float  redS[64][4];
    __shared__ float  redS2[64][4];
    ushort* Os = &P_lds[0][0][0];
    ushort* Bs = &Vt_lds[0][0][0];

    const int tid = threadIdx.x;
    const int w = tid >> 6, l = tid & 63;
    const int fr = l & 15, g = l >> 4;
    ushort (*P)[72]  = P_lds[w];
    ushort (*Vt)[72] = Vt_lds[w];

    // ===================== Phase A: attention =====================
    f32x4 o2[2][4][2] = {};

    #pragma unroll
    for (int hh = 0; hh < 2; ++hh) {
        const int h = w + hh * 4;
        const int hoff = h * 32;

        bf16x8 kf[4], qf[4];
        #pragma unroll
        for (int i = 0; i < 4; ++i) {
            int t = 16 * i + fr;
            if (CROSS && t > 48) t = 48;
            kf[i] = *reinterpret_cast<const bf16x8*>(
                ksrc + (size_t)(krow0 + t) * KSTR + hoff + g * 8);
        }
        #pragma unroll
        for (int j = 0; j < 4; ++j)
            qf[j] = *reinterpret_cast<const bf16x8*>(
                qsrc + (size_t)(qrow0 + 16 * j + fr) * QSTR + hoff + g * 8);

        // stage V transposed: Vt[d][k'], pair-packed b32 writes (wave-local)
        #pragma unroll
        for (int t2 = 0; t2 < 2; ++t2) {
            const int task = t2 * 64 + l;
            const int rp = task >> 2, cg = task & 3;
            int r0 = 2 * rp, r1 = r0 + 1;
            if (CROSS) { if (r0 > 48) r0 = 48; if (r1 > 48) r1 = 48; }
            const uint4 a = *reinterpret_cast<const uint4*>(
                vsrc + (size_t)(krow0 + r0) * KSTR + hoff + cg * 8);
            const uint4 b = *reinterpret_cast<const uint4*>(
                vsrc + (size_t)(krow0 + r1) * KSTR + hoff + cg * 8);
            const uint ac[4] = {a.x, a.y, a.z, a.w};
            const uint bc[4] = {b.x, b.y, b.z, b.w};
            #pragma unroll
            for (int k = 0; k < 4; ++k) {
                uint lo = (ac[k] & 0xFFFFu) | (bc[k] << 16);
                uint hi = (ac[k] >> 16)     | (bc[k] & 0xFFFF0000u);
                *reinterpret_cast<uint*>(&Vt[cg * 8 + 2 * k][2 * rp])     = lo;
                *reinterpret_cast<uint*>(&Vt[cg * 8 + 2 * k + 1][2 * rp]) = hi;
            }
        }

        // S^T = K @ Q^T
        f32x4 st_[4][4];
        #pragma unroll
        for (int i = 0; i < 4; ++i)
            #pragma unroll
            for (int j = 0; j < 4; ++j) {
                f32x4 z = {};
                st_[i][j] = __builtin_amdgcn_mfma_f32_16x16x32_bf16(
                    kf[i], qf[j], z, 0, 0, 0);
                st_[i][j] *= 0.17677669529663689f;
            }
        if (CROSS) {
            #pragma unroll
            for (int j = 0; j < 4; ++j)
                #pragma unroll
                for (int r = 0; r < 4; ++r)
                    if (r > 0 || g > 0) st_[3][j][r] = -1e30f;
        }

        // softmax per q-column (max-sub, normalized), pack P^T (wave-local)
        #pragma unroll
        for (int j = 0; j < 4; ++j) {
            float mx = -1e30f;
            #pragma unroll
            for (int i = 0; i < 4; ++i)
                #pragma unroll
                for (int r = 0; r < 4; ++r) mx = fmaxf(mx, st_[i][j][r]);
            mx = fmaxf(mx, __shfl_xor(mx, 16));
            mx = fmaxf(mx, __shfl_xor(mx, 32));
            float sm = 0.f;
            #pragma unroll
            for (int i = 0; i < 4; ++i)
                #pragma unroll
                for (int r = 0; r < 4; ++r) {
                    float p = __expf(st_[i][j][r] - mx);
                    st_[i][j][r] = p;
                    sm += p;
                }
            sm += __shfl_xor(sm, 16);
            sm += __shfl_xor(sm, 32);
            const float inv = 1.f / sm;
            const int q = 16 * j + fr;
            #pragma unroll
            for (int i = 0; i < 4; ++i) {
                uint lo = f2b_pk(st_[i][j][0] * inv, st_[i][j][1] * inv);
                uint hi = f2b_pk(st_[i][j][2] * inv, st_[i][j][3] * inv);
                *reinterpret_cast<uint2*>(&P[q][16 * i + 4 * g]) = make_uint2(lo, hi);
            }
        }

        __syncthreads();   // P/Vt visible

        // O = P @ V  -> o2[hh]
        #pragma unroll
        for (int s = 0; s < 2; ++s) {
            bf16x8 pa[4], vb[2];
            #pragma unroll
            for (int i = 0; i < 4; ++i)
                pa[i] = *reinterpret_cast<const bf16x8*>(&P[16 * i + fr][32 * s + 8 * g]);
            #pragma unroll
            for (int j2 = 0; j2 < 2; ++j2)
                vb[j2] = *reinterpret_cast<const bf16x8*>(&Vt[16 * j2 + fr][32 * s + 8 * g]);
            #pragma unroll
            for (int i = 0; i < 4; ++i)
                #pragma unroll
                for (int j2 = 0; j2 < 2; ++j2)
                    o2[hh][i][j2] = __builtin_amdgcn_mfma_f32_16x16x32_bf16(
                        pa[i], vb[j2], o2[hh][i][j2], 0, 0, 0);
        }
    }

    __syncthreads();   // ALL waves' P/Vt reads done -> safe to overlay Os/Bs

    // gather both heads into Os (padded stride 264): full 64x256 tile
    #pragma unroll
    for (int hh = 0; hh < 2; ++hh)
        #pragma unroll
        for (int i = 0; i < 4; ++i)
            #pragma unroll
            for (int j2 = 0; j2 < 2; ++j2)
                #pragma unroll
                for (int r = 0; r < 4; ++r)
                    Os[(16 * i + 4 * g + r) * OSTR + hh * 128 + w * 32 + 16 * j2 + fr] =
                        f2b(o2[hh][i][j2][r]);

    // ===================== Phase B: out-proj + res + LN =====================
    const int skc = (tid & 3) * 8;
    const int srB = tid >> 2;            // 0..63

    f32x4 acc[4][4] = {};
    for (int k0 = 0; k0 < 256; k0 += 32) {
        // stage W rows 0..255, cols k0..k0+31 into Bs (4 rounds)
        #pragma unroll
        for (int q = 0; q < 4; ++q)
            __builtin_amdgcn_global_load_lds(
                (const AS1 void*)(W + (size_t)(srB + q * 64) * 256 + k0 + skc),
                (AS3 void*)&Bs[(tid + q * 256) * 8], 16, 0, 0);
        __syncthreads();   // Bs ready; (k0==0) also: Os gather complete

        bf16x8 af[4], bf[4];
        #pragma unroll
        for (int i = 0; i < 4; ++i)
            af[i] = *reinterpret_cast<const bf16x8*>(&Os[(i * 16 + fr) * OSTR + k0 + g * 8]);
        #pragma unroll
        for (int j = 0; j < 4; ++j)
            bf[j] = *reinterpret_cast<const bf16x8*>(&Bs[(w * 64 + j * 16 + fr) * 32 + g * 8]);
        #pragma unroll
        for (int i = 0; i < 4; ++i)
            #pragma unroll
            for (int j = 0; j < 4; ++j)
                acc[i][j] = __builtin_amdgcn_mfma_f32_16x16x32_bf16(
                    af[i], bf[j], acc[i][j], 0, 0, 0);
        __syncthreads();   // Bs consumed (and Os reads of this k0 done)
    }

    int   col[4]; float bv[4], wv[4], lb[4];
    #pragma unroll
    for (int j = 0; j < 4; ++j) {
        col[j] = w * 64 + j * 16 + fr;
        bv[j]  = bias[col[j]];
        wv[j]  = lnw[col[j]];
        lb[j]  = lnb[col[j]];
    }

    const int row0 = qrow0;   // output rows = query rows

    // pass 1: x = acc + bias + stb(bf16); per-row partial sums -> LDS
    #pragma unroll
    for (int i = 0; i < 4; ++i)
        #pragma unroll
        for (int r = 0; r < 4; ++r) {
            const int rl = i * 16 + g * 4 + r;
            const size_t rb = (size_t)(row0 + rl) * 256;
            float s = 0.f, s2 = 0.f;
            #pragma unroll
            for (int j = 0; j < 4; ++j) {
                float x = acc[i][j][r] + bv[j] + b2f(stb[rb + col[j]]);
                acc[i][j][r] = x;
                s += x; s2 += x * x;
            }
            #pragma unroll
            for (int o = 1; o < 16; o <<= 1) {
                s  += __shfl_xor(s, o);
                s2 += __shfl_xor(s2, o);
            }
            if (fr == 0) { redS[rl][w] = s; redS2[rl][w] = s2; }
        }
    __syncthreads();

    // pass 2: normalize -> Cs (= Os region, stride OSTR; af reads all done)
    #pragma unroll
    for (int i = 0; i < 4; ++i)
        #pragma unroll
        for (int r = 0; r < 4; ++r) {
            const int rl = i * 16 + g * 4 + r;
            const float ts  = redS[rl][0] + redS[rl][1] + redS[rl][2] + redS[rl][3];
            const float ts2 = redS2[rl][0] + redS2[rl][1] + redS2[rl][2] + redS2[rl][3];
            const float mean = ts * (1.f / 256.f);
            const float var  = ts2 * (1.f / 256.f) - mean * mean;
            const float rs   = rsqrtf(var + 1e-5f);
            #pragma unroll
            for (int j = 0; j < 4; ++j) {
                const float y = (acc[i][j][r] - mean) * rs * wv[j] + lb[j];
                Os[rl * OSTR + col[j]] = f2b(y);
            }
        }
    __syncthreads();

    // coalesced stb store (64 x 256)
    #pragma unroll
    for (int it = 0; it < 8; ++it) {
        const int e = it * 256 + tid;
        const int lrow = e >> 5, lcol = (e & 31) * 8;
        *reinterpret_cast<uint4*>(&stb[(size_t)(row0 + lrow) * 256 + lcol]) =
            *reinterpret_cast<const uint4*>(&Os[lrow * OSTR + lcol]);
    }
}

// ---------------------------------------------------------------------------
// st init (bf16 only): stb[b,s,d] = init_part_tokens[s,d] + part_id_emb[s>>6,d]
// ---------------------------------------------------------------------------
__global__ __launch_bounds__(256) void init_st(
    ushort* __restrict__ stb,
    const float* __restrict__ init_tokens, const float* __restrict__ pid_emb)
{
    int i = blockIdx.x * 256 + threadIdx.x;
    int c = i & 63;
    int s = (i >> 6) & 511;
    int p = s >> 6;
    float4 v = *reinterpret_cast<const float4*>(&init_tokens[s * 256 + c * 4]);
    float4 e = *reinterpret_cast<const float4*>(&pid_emb[p * 256 + c * 4]);
    v.x += e.x; v.y += e.y; v.z += e.z; v.w += e.w;
    *reinterpret_cast<uint2*>(&stb[(size_t)i * 4]) =
        make_uint2(f2b_pk(v.x, v.y), f2b_pk(v.z, v.w));
}

// ---------------------------------------------------------------------------
// Coords head (bf16 input): out[m,n] = stb[m,:].coord_w[n,:] + coord_b[n]
// ---------------------------------------------------------------------------
__global__ __launch_bounds__(256) void coord_head(
    const ushort* __restrict__ stb, const float* __restrict__ w,
    const float* __restrict__ b, float* __restrict__ out)
{
    const int row = blockIdx.x * 8 + (threadIdx.x >> 5);
    const int l   = threadIdx.x & 31;
    const ushort* x = stb + (size_t)row * 256 + l * 8;
    uint4 xv = *reinterpret_cast<const uint4*>(x);
    float xf[8];
    const uint xc[4] = {xv.x, xv.y, xv.z, xv.w};
    #pragma unroll
    for (int k = 0; k < 4; ++k) {
        xf[2*k]   = __uint_as_float(xc[k] << 16);
        xf[2*k+1] = __uint_as_float(xc[k] & 0xFFFF0000u);
    }
    float acc[3];
    #pragma unroll
    for (int n = 0; n < 3; ++n) {
        const float* wn = w + n * 256 + l * 8;
        float4 w0 = *reinterpret_cast<const float4*>(wn);
        float4 w1 = *reinterpret_cast<const float4*>(wn + 4);
        acc[n] = xf[0]*w0.x + xf[1]*w0.y + xf[2]*w0.z + xf[3]*w0.w
               + xf[4]*w1.x + xf[5]*w1.y + xf[6]*w1.z + xf[7]*w1.w;
    }
    #pragma unroll
    for (int o = 16; o; o >>= 1)
        #pragma unroll
        for (int n = 0; n < 3; ++n) acc[n] += __shfl_xor(acc[n], o);
    if (l == 0) {
        #pragma unroll
        for (int n = 0; n < 3; ++n) out[(size_t)row * 3 + n] = acc[n] + b[n];
    }
}

// ---------------------------------------------------------------------------
extern "C" void kernel_launch(void* const* d_in, const int* in_sizes, int n_in,
                              void* d_out, int out_size, void* d_ws, size_t ws_size,
                              hipStream_t stream)
{
    const float* feat             = (const float*)d_in[0];
    const float* img_proj_w      = (const float*)d_in[1];
    const float* img_proj_b      = (const float*)d_in[2];
    const float* init_part_tokens = (const float*)d_in[3];
    const float* part_id_emb     = (const float*)d_in[4];
    const float* local_in_w      = (const float*)d_in[5];
    const float* local_in_b      = (const float*)d_in[6];
    const float* local_out_w     = (const float*)d_in[7];
    const float* local_out_b     = (const float*)d_in[8];
    const float* cross_in_w      = (const float*)d_in[9];
    const float* cross_in_b      = (const float*)d_in[10];
    const float* cross_out_w     = (const float*)d_in[11];
    const float* cross_out_b     = (const float*)d_in[12];
    const float* norm1_w         = (const float*)d_in[13];
    const float* norm1_b         = (const float*)d_in[14];
    const float* norm2_w         = (const float*)d_in[15];
    const float* norm2_b         = (const float*)d_in[16];
    const float* coord_w         = (const float*)d_in[17];
    const float* coord_b         = (const float*)d_in[18];
    float* out = (float*)d_out;

    // Workspace layout (all bf16 activations)
    ushort* stb  = (ushort*)d_ws;                      // 32768*256 bf16 state
    ushort* big  = stb  + (size_t)M_ST * D_;           // 32768*768 bf16 (qkv / q)
    ushort* kv   = big  + (size_t)M_ST * 3 * D_;       // 3136*512 (k|v image)
    ushort* fbf  = kv   + (size_t)M_IMG * 512;         // 3136*512
    ushort* img  = fbf  + (size_t)M_IMG * 512;         // 3136*256
    ushort* lw_in  = img   + (size_t)M_IMG * D_;
    ushort* lw_out = lw_in  + 768 * 256;
    ushort* cw_in  = lw_out + 256 * 256;
    ushort* cw_out = cw_in  + 768 * 256;
    ushort* iw     = cw_out + 256 * 256;

    // --- conversions (tiny) ---
    cvt_bf16x4<<<768*256/4/256, 256, 0, stream>>>((const float4*)local_in_w,  (uint2*)lw_in,  768*256/4);
    cvt_bf16x4<<<256*256/4/256, 256, 0, stream>>>((const float4*)local_out_w, (uint2*)lw_out, 256*256/4);
    cvt_bf16x4<<<768*256/4/256, 256, 0, stream>>>((const float4*)cross_in_w,  (uint2*)cw_in,  768*256/4);
    cvt_bf16x4<<<256*256/4/256, 256, 0, stream>>>((const float4*)cross_out_w, (uint2*)cw_out, 256*256/4);
    cvt_bf16x4<<<256*512/4/256, 256, 0, stream>>>((const float4*)img_proj_w,  (uint2*)iw,     256*512/4);
    cvt_bf16x4<<<(M_IMG*512/4 + 255)/256, 256, 0, stream>>>((const float4*)feat, (uint2*)fbf, M_IMG*512/4);

    // --- one-time precompute ---
    gemm_bf16<<<dim3((M_IMG+127)/128, 2), 256, 0, stream>>>(fbf, iw, img_proj_b, img, M_IMG, 256, 512);
    // combined k|v image projection: W rows 256..767 of cw_in -> kv[3136][512]
    gemm_bf16<<<dim3((M_IMG+127)/128, 4), 256, 0, stream>>>(
        img, cw_in + 256*256, cross_in_b + 256, kv, M_IMG, 512, 256);
    init_st<<<M_ST * D_ / 4 / 256, 256, 0, stream>>>(stb, init_part_tokens, part_id_emb);

    // --- 6 transformer blocks ---
    for (int i = 0; i < 6; ++i) {
        // local MHA + out-proj + res + LN
        gemm_bf16_big<<<dim3(M_ST/256, 6), 512, 0, stream>>>(stb, lw_in, local_in_b, big, 768, 256);
        attn_oln<0><<<512, 256, 0, stream>>>(big, big + 256, big + 512,
                                             lw_out, local_out_b, stb,
                                             norm1_w + i*256, norm1_b + i*256);
        // cross MHA (K/V precomputed) + out-proj + res + LN
        gemm_bf16_big<<<dim3(M_ST/256, 2), 512, 0, stream>>>(stb, cw_in, cross_in_b, big, 256, 256);
        attn_oln<1><<<512, 256, 0, stream>>>(big, kv, kv + 256,
                                             cw_out, cross_out_b, stb,
                                             norm2_w + i*256, norm2_b + i*256);
    }

    // --- coords head ---
    coord_head<<<M_ST / 8, 256, 0, stream>>>(stb, coord_w, coord_b, out);
}